// Round 10
// baseline (54669.873 us; speedup 1.0000x reference)
//
#include <hip/hip_runtime.h>
#include <hip/hip_bf16.h>

#define T_ 512
#define B_ 128
#define D_ 256
#define H_ 256
#define EPS 1e-5f

typedef __attribute__((ext_vector_type(8))) short short8;
typedef __attribute__((ext_vector_type(4))) short short4v;
typedef __attribute__((ext_vector_type(4))) float f32x4;
typedef unsigned long long ull;

// ---- weight arena: [16 slices][21 units][8 frags][64 lanes][8 elems] bf16 ----
// unit u: 0-5 gates (g=u>>1, half=u&1, K=512), 6-8 aux (Cx,Wlt,Chw),
// 9-20 trans (li=(u-9)/3, m=(u-9)%3).
#define SLICE_E  86016
#define WT_TOTAL 1376256

// ws past arena
#define PRE_OFFB   2752512UL  // f16 [8cl][2par][6arr][16row][256col] = 786432 B
#define FLAG_OFFB  3538944UL  // u32 [8cl][2par][16]
#define FLAG_BYTES 1024UL

// LDS (bytes)
#define L_XBF  0              // [16][256] bf16 x, swizzled          (8192)
#define L_HBF  8192           // [16][256] bf16 h, swizzled          (8192)
#define L_AUX  16384          // 3 units x 8192 (Cx,Wlt,Chw)         (24576)
#define L_TRN  40960          // 11 units x 8192 (trans minus li0Wr) (90112)
#define L_PARM 131072         // 27 f32 vecs x 1024B                 (27648)
#define L_END  158720

__device__ __forceinline__ short f2bf(float f) {
  unsigned u = __builtin_bit_cast(unsigned, f);
  u = (u + 0x7FFFu + ((u >> 16) & 1u)) >> 16;   // RNE
  return (short)u;
}
__device__ __forceinline__ unsigned short f2h(float f) {
  _Float16 h = (_Float16)f;                      // v_cvt_f16_f32, RNE
  return __builtin_bit_cast(unsigned short, h);
}
__device__ __forceinline__ float h2f(unsigned short u) {
  return (float)__builtin_bit_cast(_Float16, u);
}
__device__ __forceinline__ f32x4 up4(ull v) {
  f32x4 o;
  o[0] = h2f((unsigned short)v);
  o[1] = h2f((unsigned short)(v >> 16));
  o[2] = h2f((unsigned short)(v >> 32));
  o[3] = h2f((unsigned short)(v >> 48));
  return o;
}
__device__ __forceinline__ f32x4 zero4() { f32x4 z = {0.f, 0.f, 0.f, 0.f}; return z; }
__device__ __forceinline__ f32x4 mfma16(short8 a, short8 b, f32x4 c) {
  return __builtin_amdgcn_mfma_f32_16x16x32_bf16(a, b, c, 0, 0, 0);
}
__device__ __forceinline__ void waitv0() { asm volatile("s_waitcnt vmcnt(0)" ::: "memory"); }
__device__ __forceinline__ ull ald8(ull* p) {
  return __hip_atomic_load(p, __ATOMIC_RELAXED, __HIP_MEMORY_SCOPE_AGENT);
}
__device__ __forceinline__ void ast8(ull* p, ull v) {
  __hip_atomic_store(p, v, __ATOMIC_RELAXED, __HIP_MEMORY_SCOPE_AGENT);
}

// ---------------- weight prep: f32 -> bf16, frag-major slice layout ----------------
__global__ void prep_weights(const float* __restrict__ Wr, const float* __restrict__ Wz,
                             const float* __restrict__ Wl, const float* __restrict__ Wlt,
                             const float* __restrict__ Cx, const float* __restrict__ Chw,
                             const float* __restrict__ tWr, const float* __restrict__ tWz,
                             const float* __restrict__ tWc, short* __restrict__ wt) {
  int idx = blockIdx.x * 256 + threadIdx.x;
  if (idx >= WT_TOTAL) return;
  int j  = idx / SLICE_E;
  int r  = idx - j * SLICE_E;
  int u  = r >> 12;
  int rr = r & 4095;
  int kf = rr >> 9;
  int le = rr & 511;
  int l  = le >> 3, e = le & 7;
  int la = l & 15, lh = l >> 4;
  int col = j * 16 + la;
  float v;
  if (u < 6) {
    int g = u >> 1, half = u & 1;
    int k = half * 256 + lh * 8 + kf * 32 + e;
    const float* W = (g == 0) ? Wr : (g == 1 ? Wz : Wl);
    v = W[k * 256 + col];
  } else if (u < 9) {
    int a = u - 6;
    int k = lh * 8 + kf * 32 + e;
    const float* W = (a == 0) ? Cx : (a == 1 ? Wlt : Chw);
    v = W[k * 256 + col];
  } else {
    int q = u - 9;
    int li = q / 3, m = q - li * 3;
    int k = lh * 8 + kf * 32 + e;
    const float* W = (m == 0) ? tWr : (m == 1 ? tWz : tWc);
    v = W[(li * 256 + k) * 256 + col];
  }
  wt[idx] = f2bf(v);
}

// ---- merged single-sync kernel: 8 clusters x 16 col-slice WGs, 1 wave each ----
__global__ __launch_bounds__(64, 1)
void rnn_m1(const float* __restrict__ x, const int* __restrict__ lengths,
            const float* __restrict__ gr, const float* __restrict__ br,
            const float* __restrict__ gz, const float* __restrict__ bz,
            const float* __restrict__ gl, const float* __restrict__ bl,
            const float* __restrict__ Chb,
            const float* __restrict__ tgr, const float* __restrict__ tbr,
            const float* __restrict__ tgz, const float* __restrict__ tbz,
            const float* __restrict__ tbc,
            const short* __restrict__ W, ull* __restrict__ pre8,
            unsigned* __restrict__ flags, float* __restrict__ out) {

  __shared__ __align__(16) char smem[L_END];

  const int l  = threadIdx.x;
  const int la = l & 15, lh = l >> 4;
  const int amask = (la & 7) << 4;
  const int bid = blockIdx.x;
  const int cl = bid & 7, j = bid >> 3;
  const int rb0 = cl * 16;
  const int myrow = l >> 2, cq = l & 3;
  const int colb = cq * 64;

  const short* Wsl = W + (size_t)j * SLICE_E;

  // resident weights: aux(6,7,8) + trans units 10..20
  #pragma unroll 1
  for (int u = 0; u < 14; ++u) {
    char* dst = smem + ((u < 3) ? (L_AUX + u * 8192) : (L_TRN + (u - 3) * 8192));
    const short* src = Wsl + (size_t)((u < 3) ? (u + 6) : (u + 7)) * 4096;
    #pragma unroll
    for (int kf = 0; kf < 8; ++kf)
      *(short8*)(dst + kf * 1024 + l * 16) = *(const short8*)(src + kf * 512 + l * 8);
  }
  // params -> LDS (f32): 0..6 = gr,br,gz,bz,gl,bl,Chb ; 7+li*5+{tgr,tbr,tgz,tbz,tbc}
  {
    const float* b7[7] = {gr, br, gz, bz, gl, bl, Chb};
    #pragma unroll
    for (int v = 0; v < 7; ++v)
      *(f32x4*)(smem + L_PARM + (v * 256 + 4 * l) * 4) = *(const f32x4*)(b7[v] + 4 * l);
    const float* bt5[5] = {tgr, tbr, tgz, tbz, tbc};
    #pragma unroll
    for (int li = 0; li < 4; ++li)
      #pragma unroll
      for (int v = 0; v < 5; ++v)
        *(f32x4*)(smem + L_PARM + ((7 + li * 5 + v) * 256 + 4 * l) * 4) =
            *(const f32x4*)(bt5[v] + li * 256 + 4 * l);
  }
  for (int i = l; i < 1024; i += 64) ((short4v*)(smem + L_HBF))[i] = (short4v){0, 0, 0, 0};

  int maxlen = 0;
  for (int i = 0; i < 16; ++i) {
    int v = lengths[rb0 + i];
    maxlen = maxlen > v ? maxlen : v;
  }
  const int mylen = lengths[rb0 + myrow];

  unsigned* flc = flags + cl * 32;         // [2 par][16]
  int dead = 0;

  auto pollf = [&](int par, unsigned tag) {
    if (!dead && l < 16) {
      unsigned* sp = flc + par * 16 + l;
      int it = 0;
      while (__hip_atomic_load(sp, __ATOMIC_RELAXED, __HIP_MEMORY_SCOPE_AGENT) < tag) {
        if (++it > 300000) { dead = 1; break; }
        __builtin_amdgcn_s_sleep(1);
      }
    }
    asm volatile("" ::: "memory");
  };
  auto ldu = [&](short8 (&dst)[8], const short* bp) {
    #pragma unroll
    for (int kf = 0; kf < 8; ++kf) dst[kf] = *(const short8*)(bp + kf * 512 + l * 8);
  };
  auto mm8r = [&](short8 (&Bv)[8], f32x4& acc, int Ab) {
    #pragma unroll
    for (int kf = 0; kf < 8; ++kf) {
      int aoff = Ab + la * 512 + (((kf * 64) + lh * 16) ^ amask);
      acc = mfma16(*(const short8*)(smem + aoff), Bv[kf], acc);
    }
  };
  auto mmlds = [&](int Bub, f32x4& acc, int Ab) {
    #pragma unroll
    for (int kf = 0; kf < 8; ++kf) {
      int aoff = Ab + la * 512 + (((kf * 64) + lh * 16) ^ amask);
      short8 bv = *(const short8*)(smem + Bub + kf * 1024 + l * 16);
      acc = mfma16(*(const short8*)(smem + aoff), bv, acc);
    }
  };
  // pack my 16-col preact slice to f16 and post (8B agent stores on la%4==0 lanes)
  auto postarr = [&](ull* preB, int arr, f32x4 acc) {
    #pragma unroll
    for (int i = 0; i < 4; ++i) {
      unsigned short h = f2h(acc[i]);
      int o1 = __shfl_xor((int)(unsigned)h, 1);
      unsigned p2 = (la & 1) ? (((unsigned)o1 & 0xffffu) | ((unsigned)h << 16))
                             : ((unsigned)h | ((unsigned)o1 << 16));
      int o2 = __shfl_xor((int)p2, 2);
      if ((la & 3) == 0) {
        ull v = (ull)p2 | ((ull)(unsigned)o2 << 32);
        int row = lh * 4 + i;
        ast8(preB + (size_t)(arr * 16 + row) * 64 + j * 4 + (la >> 2), v);
      }
    }
  };
  auto stageX = [&](int t) {
    const float* xs = x + ((size_t)t * B_ + rb0 + myrow) * D_ + colb;
    #pragma unroll
    for (int u2 = 0; u2 < 8; ++u2) {
      f32x4 a = *(const f32x4*)(xs + u2 * 8);
      f32x4 b = *(const f32x4*)(xs + u2 * 8 + 4);
      short8 s;
      s[0] = f2bf(a[0]); s[1] = f2bf(a[1]); s[2] = f2bf(a[2]); s[3] = f2bf(a[3]);
      s[4] = f2bf(b[0]); s[5] = f2bf(b[1]); s[6] = f2bf(b[2]); s[7] = f2bf(b[3]);
      *(short8*)(smem + L_XBF + myrow * 512 + ((colb * 2 + u2 * 16) ^ ((myrow & 7) << 4))) = s;
    }
  };

  short8 B0[8], B1[8];
  ldu(B0, Wsl);                // gates g0 x-half
  ldu(B1, Wsl + 4096);         // gates g0 h-half

  f32x4 hr[16];                // f32 h for (myrow, cols 64cq..64cq+63), identical on all WGs
  #pragma unroll
  for (int k = 0; k < 16; ++k) hr[k] = zero4();

  for (int t = 0; t < maxlen; ++t) {
    const bool act = t < mylen;
    // ============================ round G ============================
    {
      int R = t * 5, par = R & 1;
      unsigned tag = (unsigned)(R + 1);
      ull* preB = pre8 + ((size_t)cl * 2 + par) * 6144;
      stageX(t);
      f32x4 ac[6];
      #pragma unroll
      for (int a2 = 0; a2 < 6; ++a2) ac[a2] = zero4();
      mm8r(B0, ac[0], L_XBF); ldu(B0, Wsl + 2 * 4096);
      mm8r(B1, ac[0], L_HBF); ldu(B1, Wsl + 3 * 4096);
      mm8r(B0, ac[1], L_XBF); ldu(B0, Wsl + 4 * 4096);
      mm8r(B1, ac[1], L_HBF); ldu(B1, Wsl + 5 * 4096);
      mm8r(B0, ac[2], L_XBF);
      mm8r(B1, ac[2], L_HBF);
      mmlds(L_AUX,         ac[3], L_XBF);   // xcx
      mmlds(L_AUX + 8192,  ac[4], L_XBF);   // xwl
      mmlds(L_AUX + 16384, ac[5], L_HBF);   // hch
      #pragma unroll
      for (int a2 = 0; a2 < 6; ++a2) postarr(preB, a2, ac[a2]);
      waitv0();
      if (l == 0)
        __hip_atomic_store(flc + par * 16 + j, tag, __ATOMIC_RELAXED, __HIP_MEMORY_SCOPE_AGENT);
      ldu(B0, Wsl + 9 * 4096);             // li0 tWr prefetch under poll
      pollf(par, tag);

      // read full f16 preacts for (myrow, my 64 cols)
      ull a0[16], a1[16], a2r[16], a3[16], a4[16], a5[16];
      {
        ull* pb = preB + (size_t)myrow * 64 + cq * 16;
        #pragma unroll
        for (int k = 0; k < 16; ++k) {
          a0[k]  = ald8(pb + k);
          a1[k]  = ald8(pb + 1024 + k);
          a2r[k] = ald8(pb + 2048 + k);
          a3[k]  = ald8(pb + 3072 + k);
          a4[k]  = ald8(pb + 4096 + k);
          a5[k]  = ald8(pb + 5120 + k);
        }
      }
      // redundant LN stats (identical order on every WG)
      float s1[3] = {0.f, 0.f, 0.f}, s2[3] = {0.f, 0.f, 0.f};
      #pragma unroll
      for (int k = 0; k < 16; ++k) {
        f32x4 v0 = up4(a0[k]), v1 = up4(a1[k]), v2 = up4(a2r[k]);
        #pragma unroll
        for (int e = 0; e < 4; ++e) {
          s1[0] += v0[e]; s2[0] += v0[e] * v0[e];
          s1[1] += v1[e]; s2[1] += v1[e] * v1[e];
          s1[2] += v2[e]; s2[2] += v2[e] * v2[e];
        }
      }
      #pragma unroll
      for (int g2 = 0; g2 < 3; ++g2) {
        s1[g2] += __shfl_xor(s1[g2], 1); s2[g2] += __shfl_xor(s2[g2], 1);
        s1[g2] += __shfl_xor(s1[g2], 2); s2[g2] += __shfl_xor(s2[g2], 2);
      }
      float m3[3], rs3[3];
      #pragma unroll
      for (int g2 = 0; g2 < 3; ++g2) {
        float mm = s1[g2] * (1.f / 256.f);
        float vv = s2[g2] * (1.f / 256.f) - mm * mm;
        m3[g2] = mm; rs3[g2] = rsqrtf((vv > 0.f ? vv : 0.f) + EPS);
      }
      // redundant full elementwise
      short4v lo;
      #pragma unroll
      for (int k = 0; k < 16; ++k) {
        int cb = colb + 4 * k;
        f32x4 P0 = up4(a0[k]), P1 = up4(a1[k]), P2 = up4(a2r[k]);
        f32x4 P3 = up4(a3[k]), P4 = up4(a4[k]), P5 = up4(a5[k]);
        f32x4 g4r = *(const f32x4*)(smem + L_PARM + (0 * 256 + cb) * 4);
        f32x4 b4r = *(const f32x4*)(smem + L_PARM + (1 * 256 + cb) * 4);
        f32x4 g4z = *(const f32x4*)(smem + L_PARM + (2 * 256 + cb) * 4);
        f32x4 b4z = *(const f32x4*)(smem + L_PARM + (3 * 256 + cb) * 4);
        f32x4 g4l = *(const f32x4*)(smem + L_PARM + (4 * 256 + cb) * 4);
        f32x4 b4l = *(const f32x4*)(smem + L_PARM + (5 * 256 + cb) * 4);
        f32x4 cb4 = *(const f32x4*)(smem + L_PARM + (6 * 256 + cb) * 4);
        f32x4 h = hr[k], hf;
        #pragma unroll
        for (int e = 0; e < 4; ++e) {
          float rv = 1.f / (1.f + __expf(-((P0[e] - m3[0]) * rs3[0] * g4r[e] + b4r[e])));
          float zv = 1.f / (1.f + __expf(-((P1[e] - m3[1]) * rs3[1] * g4z[e] + b4z[e])));
          float lv = 1.f / (1.f + __expf(-((P2[e] - m3[2]) * rs3[2] * g4l[e] + b4l[e])));
          float n  = tanhf(P3[e] + rv * (P5[e] + cb4[e])) + lv * P4[e];
          float hn = (1.f - zv) * h[e] + zv * n;
          hf[e] = act ? hn : h[e];
        }
        hr[k] = hf;
        short4v cur = {f2bf(hf[0]), f2bf(hf[1]), f2bf(hf[2]), f2bf(hf[3])};
        if (k & 1) {
          short8 s8 = {lo[0], lo[1], lo[2], lo[3], cur[0], cur[1], cur[2], cur[3]};
          *(short8*)(smem + L_HBF + myrow * 512 +
                     ((128 * cq + 8 * (k - 1)) ^ ((myrow & 7) << 4))) = s8;
        } else lo = cur;
      }
    }

    // ======================== transition layers ========================
    #pragma unroll 1
    for (int li = 0; li < 4; ++li) {
      int R = t * 5 + 1 + li, par = R & 1;
      unsigned tag = (unsigned)(R + 1);
      ull* preB = pre8 + ((size_t)cl * 2 + par) * 6144;
      f32x4 tc0 = zero4(), tc1 = zero4(), tc2 = zero4();
      if (li == 0) {
        mm8r(B0, tc0, L_HBF);                       // tWr (streamed)
        mmlds(L_TRN,        tc1, L_HBF);            // tWz
        mmlds(L_TRN + 8192, tc2, L_HBF);            // tWc
      } else {
        int s0 = li * 3 - 1;
        mmlds(L_TRN + (s0 + 0) * 8192, tc0, L_HBF);
        mmlds(L_TRN + (s0 + 1) * 8192, tc1, L_HBF);
        mmlds(L_TRN + (s0 + 2) * 8192, tc2, L_HBF);
      }
      postarr(preB, 0, tc0); postarr(preB, 1, tc1); postarr(preB, 2, tc2);
      waitv0();
      if (l == 0)
        __hip_atomic_store(flc + par * 16 + j, tag, __ATOMIC_RELAXED, __HIP_MEMORY_SCOPE_AGENT);
      if (li == 3) { ldu(B0, Wsl); ldu(B1, Wsl + 4096); }  // next-step gates g0
      pollf(par, tag);

      ull a0[16], a1[16], a2r[16];
      {
        ull* pb = preB + (size_t)myrow * 64 + cq * 16;
        #pragma unroll
        for (int k = 0; k < 16; ++k) {
          a0[k]  = ald8(pb + k);
          a1[k]  = ald8(pb + 1024 + k);
          a2r[k] = ald8(pb + 2048 + k);
        }
      }
      float s1[2] = {0.f, 0.f}, s2[2] = {0.f, 0.f};
      #pragma unroll
      for (int k = 0; k < 16; ++k) {
        f32x4 v0 = up4(a0[k]), v1 = up4(a1[k]);
        #pragma unroll
        for (int e = 0; e < 4; ++e) {
          s1[0] += v0[e]; s2[0] += v0[e] * v0[e];
          s1[1] += v1[e]; s2[1] += v1[e] * v1[e];
        }
      }
      #pragma unroll
      for (int g2 = 0; g2 < 2; ++g2) {
        s1[g2] += __shfl_xor(s1[g2], 1); s2[g2] += __shfl_xor(s2[g2], 1);
        s1[g2] += __shfl_xor(s1[g2], 2); s2[g2] += __shfl_xor(s2[g2], 2);
      }
      float m2[2], rs2[2];
      #pragma unroll
      for (int g2 = 0; g2 < 2; ++g2) {
        float mm = s1[g2] * (1.f / 256.f);
        float vv = s2[g2] * (1.f / 256.f) - mm * mm;
        m2[g2] = mm; rs2[g2] = rsqrtf((vv > 0.f ? vv : 0.f) + EPS);
      }
      int pbase = 7 + li * 5;
      short4v lo;
      #pragma unroll
      for (int k = 0; k < 16; ++k) {
        int cb = colb + 4 * k;
        f32x4 P0 = up4(a0[k]), P1 = up4(a1[k]), P2 = up4(a2r[k]);
        f32x4 g4r = *(const f32x4*)(smem + L_PARM + ((pbase + 0) * 256 + cb) * 4);
        f32x4 b4r = *(const f32x4*)(smem + L_PARM + ((pbase + 1) * 256 + cb) * 4);
        f32x4 g4z = *(const f32x4*)(smem + L_PARM + ((pbase + 2) * 256 + cb) * 4);
        f32x4 b4z = *(const f32x4*)(smem + L_PARM + ((pbase + 3) * 256 + cb) * 4);
        f32x4 cb4 = *(const f32x4*)(smem + L_PARM + ((pbase + 4) * 256 + cb) * 4);
        f32x4 h = hr[k], hf;
        #pragma unroll
        for (int e = 0; e < 4; ++e) {
          float rv = 1.f / (1.f + __expf(-((P0[e] - m2[0]) * rs2[0] * g4r[e] + b4r[e])));
          float zv = 1.f / (1.f + __expf(-((P1[e] - m2[1]) * rs2[1] * g4z[e] + b4z[e])));
          float n  = tanhf(rv * (P2[e] + cb4[e]));
          float hn = (1.f - zv) * n + zv * h[e];
          hf[e] = act ? hn : h[e];
        }
        hr[k] = hf;
        if (li == 3 && cq == (j >> 2) && (k >> 2) == (j & 3)) {
          f32x4 o;
          #pragma unroll
          for (int e = 0; e < 4; ++e) o[e] = act ? hf[e] : 0.f;
          *(f32x4*)(out + ((size_t)t * B_ + rb0 + myrow) * H_ + cb) = o;
        }
        short4v cur = {f2bf(hf[0]), f2bf(hf[1]), f2bf(hf[2]), f2bf(hf[3])};
        if (k & 1) {
          short8 s8 = {lo[0], lo[1], lo[2], lo[3], cur[0], cur[1], cur[2], cur[3]};
          *(short8*)(smem + L_HBF + myrow * 512 +
                     ((128 * cq + 8 * (k - 1)) ^ ((myrow & 7) << 4))) = s8;
        } else lo = cur;
      }
    }
  }

  // tail: zero my 16-col slice past cluster maxlen
  for (int t2 = maxlen; t2 < T_; ++t2) {
    if (l < 16) {
      float* o = out + ((size_t)t2 * B_ + rb0 + l) * H_ + j * 16;
      #pragma unroll
      for (int c = 0; c < 4; ++c) *(f32x4*)(o + 4 * c) = zero4();
    }
  }
}

extern "C" void kernel_launch(void* const* d_in, const int* in_sizes, int n_in,
                              void* d_out, int out_size, void* d_ws, size_t ws_size,
                              hipStream_t stream) {
  const float* x    = (const float*)d_in[0];
  const int* lengths = (const int*)d_in[1];
  const float* Wr   = (const float*)d_in[2];
  const float* gr   = (const float*)d_in[3];
  const float* br   = (const float*)d_in[4];
  const float* Wz   = (const float*)d_in[5];
  const float* gz   = (const float*)d_in[6];
  const float* bz   = (const float*)d_in[7];
  const float* Wl   = (const float*)d_in[8];
  const float* gl   = (const float*)d_in[9];
  const float* bl   = (const float*)d_in[10];
  const float* Wlt  = (const float*)d_in[11];
  const float* Cx   = (const float*)d_in[12];
  const float* Chw  = (const float*)d_in[13];
  const float* Chb  = (const float*)d_in[14];
  const float* tWr  = (const float*)d_in[15];
  const float* tgr  = (const float*)d_in[16];
  const float* tbr  = (const float*)d_in[17];
  const float* tWz  = (const float*)d_in[18];
  const float* tgz  = (const float*)d_in[19];
  const float* tbz  = (const float*)d_in[20];
  const float* tWc  = (const float*)d_in[21];
  const float* tbc  = (const float*)d_in[22];

  short*    wt    = (short*)d_ws;
  ull*      pre8  = (ull*)((char*)d_ws + PRE_OFFB);
  unsigned* flags = (unsigned*)((char*)d_ws + FLAG_OFFB);

  hipMemsetAsync(flags, 0, FLAG_BYTES, stream);
  hipLaunchKernelGGL(prep_weights, dim3((WT_TOTAL + 255) / 256), dim3(256), 0, stream,
                     Wr, Wz, Wl, Wlt, Cx, Chw, tWr, tWz, tWc, wt);
  hipLaunchKernelGGL(rnn_m1, dim3(128), dim3(64), 0, stream,
                     x, lengths, gr, br, gz, bz, gl, bl, Chb,
                     tgr, tbr, tgz, tbz, tbc, wt, pre8, flags, (float*)d_out);
}

// Round 11
// 17891.652 us; speedup vs baseline: 3.0556x; 3.0556x over previous
//
#include <hip/hip_runtime.h>
#include <hip/hip_bf16.h>

#define T_ 512
#define B_ 128
#define D_ 256
#define H_ 256
#define EPS 1e-5f

typedef __attribute__((ext_vector_type(8))) short short8;
typedef __attribute__((ext_vector_type(4))) short short4v;
typedef __attribute__((ext_vector_type(4))) float f32x4;
typedef __attribute__((ext_vector_type(4))) unsigned u32x4;
typedef unsigned long long ull;

// ---- weight arena: [16 slices][21 units][8 frags][64 lanes][8 elems] bf16 ----
// slice j = h-cols [16j,16j+16). unit u: 0-5 gates (g=u>>1, half=u&1, K=512),
// 6-8 aux (Cx,Wlt,Chw, K=256), 9-20 trans (li=(u-9)/3, m=(u-9)%3, K=256).
#define SLICE_E  86016
#define WT_TOTAL 1376256

// ws byte offsets past arena
#define STATS_OFFB 2752512UL  // f32 [8cl][2par][96 slot][16 wg]        (98304 B)
#define HX_OFFB    2850816UL  // ull  [8cl][2par][16 row][128 pair]     (262144 B)
#define FLAG_OFFB  3112960UL  // u32  [8cl][2par][16 wg]                (1024 B)
#define SYNC0_OFFB HX_OFFB
#define SYNC0_BYTES (262144UL + 1024UL)

// LDS layout (bytes) — identical to r7
#define L_XBF  0        // [16][256] bf16 x, XOR-swizzled      (8192)
#define L_HBF  8192     // [16][256] bf16 h, XOR-swizzled      (8192)
#define L_G6   16384    // f32 [6][16][16] preact redistribute (6144)
#define L_SRED 22528    // f32 [96] reduced stats              (512)
#define L_AUX  23040    // 3 units x 8192 (Cx,Wlt,Chw)         (24576)
#define L_TRN  47616    // 12 units x 8192 (transitions)       (98304)
#define L_END  145920

__device__ __forceinline__ short f2bf(float f) {
  unsigned u = __builtin_bit_cast(unsigned, f);
  u = (u + 0x7FFFu + ((u >> 16) & 1u)) >> 16;   // RNE
  return (short)u;
}
__device__ __forceinline__ f32x4 zero4() { f32x4 z = {0.f, 0.f, 0.f, 0.f}; return z; }
__device__ __forceinline__ f32x4 mfma16(short8 a, short8 b, f32x4 c) {
  return __builtin_amdgcn_mfma_f32_16x16x32_bf16(a, b, c, 0, 0, 0);
}
__device__ __forceinline__ void waitv0() { asm volatile("s_waitcnt vmcnt(0)" ::: "memory"); }

// MALL-coherent (agent scope) primitives — correct under ANY WG placement
__device__ __forceinline__ f32x4 ald4(float* p) {
  ull* q = (ull*)p;
  ull a = __hip_atomic_load(q,     __ATOMIC_RELAXED, __HIP_MEMORY_SCOPE_AGENT);
  ull b = __hip_atomic_load(q + 1, __ATOMIC_RELAXED, __HIP_MEMORY_SCOPE_AGENT);
  f32x4 v;
  v[0] = __builtin_bit_cast(float, (unsigned)(a & 0xffffffffu));
  v[1] = __builtin_bit_cast(float, (unsigned)(a >> 32));
  v[2] = __builtin_bit_cast(float, (unsigned)(b & 0xffffffffu));
  v[3] = __builtin_bit_cast(float, (unsigned)(b >> 32));
  return v;
}
__device__ __forceinline__ void ast1f(float* p, float v) {
  __hip_atomic_store((unsigned*)p, __builtin_bit_cast(unsigned, v),
                     __ATOMIC_RELAXED, __HIP_MEMORY_SCOPE_AGENT);
}
__device__ __forceinline__ ull ald8(ull* p) {
  return __hip_atomic_load(p, __ATOMIC_RELAXED, __HIP_MEMORY_SCOPE_AGENT);
}
__device__ __forceinline__ void ast8(ull* p, ull v) {
  __hip_atomic_store(p, v, __ATOMIC_RELAXED, __HIP_MEMORY_SCOPE_AGENT);
}

// ---------------- weight prep: f32 -> bf16, frag-major slice layout ----------------
__global__ void prep_weights(const float* __restrict__ Wr, const float* __restrict__ Wz,
                             const float* __restrict__ Wl, const float* __restrict__ Wlt,
                             const float* __restrict__ Cx, const float* __restrict__ Chw,
                             const float* __restrict__ tWr, const float* __restrict__ tWz,
                             const float* __restrict__ tWc, short* __restrict__ wt) {
  int idx = blockIdx.x * 256 + threadIdx.x;
  if (idx >= WT_TOTAL) return;
  int j  = idx / SLICE_E;
  int r  = idx - j * SLICE_E;
  int u  = r >> 12;
  int rr = r & 4095;
  int kf = rr >> 9;
  int le = rr & 511;
  int l  = le >> 3, e = le & 7;
  int la = l & 15, lh = l >> 4;
  int col = j * 16 + la;
  float v;
  if (u < 6) {
    int g = u >> 1, half = u & 1;
    int k = half * 256 + lh * 8 + kf * 32 + e;
    const float* W = (g == 0) ? Wr : (g == 1 ? Wz : Wl);
    v = W[k * 256 + col];
  } else if (u < 9) {
    int a = u - 6;
    int k = lh * 8 + kf * 32 + e;
    const float* W = (a == 0) ? Cx : (a == 1 ? Wlt : Chw);
    v = W[k * 256 + col];
  } else {
    int q = u - 9;
    int li = q / 3, m = q - li * 3;
    int k = lh * 8 + kf * 32 + e;
    const float* W = (m == 0) ? tWr : (m == 1 ? tWz : tWc);
    v = W[(li * 256 + k) * 256 + col];
  }
  wt[idx] = f2bf(v);
}

// ------- r7 structure: 8 clusters x 16 col-slice WGs, 1 wave each.
// stats chain = r7 flag protocol; h chain = tagged pairs + selective-retry read.
__global__ __launch_bounds__(64)
void rnn_sx(const float* __restrict__ x, const int* __restrict__ lengths,
            const float* __restrict__ gr, const float* __restrict__ br,
            const float* __restrict__ gz, const float* __restrict__ bz,
            const float* __restrict__ gl, const float* __restrict__ bl,
            const float* __restrict__ Chb,
            const float* __restrict__ tgr, const float* __restrict__ tbr,
            const float* __restrict__ tgz, const float* __restrict__ tbz,
            const float* __restrict__ tbc,
            const short* __restrict__ W, float* __restrict__ stats,
            ull* __restrict__ hx8, unsigned* __restrict__ flags,
            float* __restrict__ out) {

  __shared__ __align__(16) char smem[L_END];

  const int l  = threadIdx.x;            // single wave
  const int la = l & 15, lh = l >> 4;
  const int amask = (la & 7) << 4;
  const int bid = blockIdx.x;
  const int cl = bid & 7, j = bid >> 3;
  const int rb0 = cl * 16;
  const int myrow = l >> 2, mc = (l & 3) * 4;
  const int cg = j * 16 + mc;            // my 4 global h-cols
  const int colb = (l & 3) * 64;         // staging: my 64-col block of row myrow

  const short* Wsl = W + (size_t)j * SLICE_E;

  // ---- load resident weights (aux + transitions, 120KB) into LDS ----
  #pragma unroll 1
  for (int u = 0; u < 15; ++u) {
    char* dst = smem + ((u < 3) ? (L_AUX + u * 8192) : (L_TRN + (u - 3) * 8192));
    const short* src = Wsl + (size_t)(u + 6) * 4096;
    #pragma unroll
    for (int kf = 0; kf < 8; ++kf)
      *(short8*)(dst + kf * 1024 + l * 16) = *(const short8*)(src + kf * 512 + l * 8);
  }
  for (int i = l; i < 1024; i += 64) ((short4v*)(smem + L_HBF))[i] = (short4v){0, 0, 0, 0};

  int maxlen = 0;
  for (int i = 0; i < 16; ++i) {
    int v = lengths[rb0 + i];
    maxlen = maxlen > v ? maxlen : v;
  }
  const int mylen = lengths[rb0 + myrow];

  float* stc = stats + (size_t)(cl * 2) * 1536;    // + par*1536: [96 slot][16 wg] f32
  ull*   hxc = hx8 + (size_t)cl * 4096;            // + par*2048: [16 row][128 pair]
  unsigned* flc = flags + cl * 32;                 // [2 par][16]

  f32x4 hreg = zero4();                            // my (row, 4 cols) f32 h
  int dead = 0;

  // stats flag poll (r7 protocol + spin-first)
  auto pollf = [&](int par, unsigned tag) {
    if (!dead && l < 16) {
      unsigned* sp = flc + par * 16 + l;
      int it = 0;
      while (__hip_atomic_load(sp, __ATOMIC_RELAXED, __HIP_MEMORY_SCOPE_AGENT) < tag) {
        if (++it > 300000) { dead = 1; break; }
        if (it > 4) __builtin_amdgcn_s_sleep(1);
      }
    }
    asm volatile("" ::: "memory");
  };
  auto ldu = [&](short8 (&dst)[8], const short* bp) {     // one 8KB B-unit -> regs
    #pragma unroll
    for (int kf = 0; kf < 8; ++kf) dst[kf] = *(const short8*)(bp + kf * 512 + l * 8);
  };
  auto mm8r = [&](short8 (&Bv)[8], f32x4& acc, int Ab) {  // B regs, A from LDS
    #pragma unroll
    for (int kf = 0; kf < 8; ++kf) {
      int aoff = Ab + la * 512 + (((kf * 64) + lh * 16) ^ amask);
      acc = mfma16(*(const short8*)(smem + aoff), Bv[kf], acc);
    }
  };
  auto mmlds = [&](int Bub, f32x4& acc, int Ab) {         // B and A from LDS
    #pragma unroll
    for (int kf = 0; kf < 8; ++kf) {
      int aoff = Ab + la * 512 + (((kf * 64) + lh * 16) ^ amask);
      short8 bv = *(const short8*)(smem + Bub + kf * 1024 + l * 16);
      acc = mfma16(*(const short8*)(smem + aoff), bv, acc);
    }
  };
  auto g6store = [&](int arr, f32x4 acc) {
    #pragma unroll
    for (int i = 0; i < 4; ++i)
      *(float*)(smem + L_G6 + ((arr * 16 + lh * 4 + i) * 16 + la) * 4) = acc[i];
  };
  // post my h (row, 4 cols) as 2 tagged pairs {2xbf16, tag}
  auto posth = [&](int par, unsigned tag) {
    unsigned lo0 = (unsigned)(unsigned short)f2bf(hreg[0]) |
                   ((unsigned)(unsigned short)f2bf(hreg[1]) << 16);
    unsigned lo1 = (unsigned)(unsigned short)f2bf(hreg[2]) |
                   ((unsigned)(unsigned short)f2bf(hreg[3]) << 16);
    ull* hp = hxc + par * 2048 + myrow * 128 + j * 8 + (l & 3) * 2;
    ast8(hp,     (ull)lo0 | ((ull)tag << 32));
    ast8(hp + 1, (ull)lo1 | ((ull)tag << 32));
  };
  // speculative tagged h' read with selective retry; scatter to swizzled HBF
  auto readhx = [&](int par, unsigned tag) {
    int row2 = l >> 2;
    ull* hp = hxc + par * 2048 + row2 * 128 + (l & 3) * 32;
    unsigned lo[32];
    bool ok = false;
    int it = 0;
    for (;;) {
      if (!ok) {
        unsigned mn = 0xffffffffu;
        #pragma unroll
        for (int k = 0; k < 32; ++k) {
          ull v = ald8(hp + k);
          lo[k] = (unsigned)v;
          unsigned tg = (unsigned)(v >> 32);
          mn = mn < tg ? mn : tg;
        }
        ok = (mn >= tag);
      }
      if (__all((int)ok) || dead) break;
      if (++it > 100000) dead = 1;
      if (it > 4) __builtin_amdgcn_s_sleep(1);
    }
    #pragma unroll
    for (int q = 0; q < 8; ++q) {
      u32x4 v = { lo[4 * q], lo[4 * q + 1], lo[4 * q + 2], lo[4 * q + 3] };
      *(u32x4*)(smem + L_HBF + row2 * 512 + (((l & 3) * 128 + q * 16) ^ ((row2 & 7) << 4))) = v;
    }
  };

  short8 B0[8], B1[8];
  ldu(B0, Wsl);                 // gates g0 x-half
  ldu(B1, Wsl + 4096);          // gates g0 h-half

  for (int t = 0; t < maxlen; ++t) {
    // ============================ round G ============================
    int R = t * 5, par = R & 1;
    unsigned tag = (unsigned)(R + 1);
    // stage x_t -> XBF (bf16, swizzled); lane covers (row l>>2, 64 cols)
    {
      const float* xs = x + ((size_t)t * B_ + rb0 + (l >> 2)) * D_ + colb;
      int row2 = l >> 2;
      #pragma unroll
      for (int u2 = 0; u2 < 8; ++u2) {
        f32x4 a = *(const f32x4*)(xs + u2 * 8);
        f32x4 b = *(const f32x4*)(xs + u2 * 8 + 4);
        short8 s;
        s[0] = f2bf(a[0]); s[1] = f2bf(a[1]); s[2] = f2bf(a[2]); s[3] = f2bf(a[3]);
        s[4] = f2bf(b[0]); s[5] = f2bf(b[1]); s[6] = f2bf(b[2]); s[7] = f2bf(b[3]);
        *(short8*)(smem + L_XBF + row2 * 512 + ((colb * 2 + u2 * 16) ^ ((row2 & 7) << 4))) = s;
      }
    }
    // mm: 3 gate cols-tiles (K=512) + 3 aux tiles (K=256), all for my 16 cols
    f32x4 ac[6];
    #pragma unroll
    for (int a2 = 0; a2 < 6; ++a2) ac[a2] = zero4();
    mm8r(B0, ac[0], L_XBF); ldu(B0, Wsl + 2 * 4096);
    mm8r(B1, ac[0], L_HBF); ldu(B1, Wsl + 3 * 4096);
    mm8r(B0, ac[1], L_XBF); ldu(B0, Wsl + 4 * 4096);
    mm8r(B1, ac[1], L_HBF); ldu(B1, Wsl + 5 * 4096);
    mm8r(B0, ac[2], L_XBF);
    mm8r(B1, ac[2], L_HBF);
    mmlds(L_AUX,         ac[3], L_XBF);   // xcx
    mmlds(L_AUX + 8192,  ac[4], L_XBF);   // xwl
    mmlds(L_AUX + 16384, ac[5], L_HBF);   // hch
    #pragma unroll
    for (int a2 = 0; a2 < 6; ++a2) g6store(a2, ac[a2]);
    // my-row preacts
    f32x4 pv[6];
    #pragma unroll
    for (int a2 = 0; a2 < 6; ++a2)
      pv[a2] = *(const f32x4*)(smem + L_G6 + ((a2 * 16 + myrow) * 16 + mc) * 4);
    // partial LN stats over my WG's 16 cols (4-lane row group)
    float st[6];
    #pragma unroll
    for (int g2 = 0; g2 < 3; ++g2) {
      f32x4 v = pv[g2];
      st[2 * g2]     = v[0] + v[1] + v[2] + v[3];
      st[2 * g2 + 1] = v[0] * v[0] + v[1] * v[1] + v[2] * v[2] + v[3] * v[3];
    }
    #pragma unroll
    for (int s2 = 0; s2 < 6; ++s2) {
      st[s2] += __shfl_xor(st[s2], 1);
      st[s2] += __shfl_xor(st[s2], 2);
    }
    float* sp = stc + par * 1536;
    {
      int k4 = l & 3;
      ast1f(sp + (k4 * 16 + myrow) * 16 + j, st[k4]);
      if (k4 < 2) ast1f(sp + ((4 + k4) * 16 + myrow) * 16 + j, st[4 + k4]);
    }
    waitv0();
    if (l == 0)
      __hip_atomic_store(flc + par * 16 + j, tag, __ATOMIC_RELAXED, __HIP_MEMORY_SCOPE_AGENT);
    pollf(par, tag);
    // reduce stats: lane handles p=l (and p=64+l for l<32)
    {
      float* q = sp + l * 16;
      f32x4 a = ald4(q), b = ald4(q + 4), c = ald4(q + 8), d = ald4(q + 12);
      f32x4 s4 = a + b + c + d;
      *(float*)(smem + L_SRED + l * 4) = s4[0] + s4[1] + s4[2] + s4[3];
      if (l < 32) {
        float* q2 = sp + (64 + l) * 16;
        f32x4 a2 = ald4(q2), b2 = ald4(q2 + 4), c2 = ald4(q2 + 8), d2 = ald4(q2 + 12);
        f32x4 t4 = a2 + b2 + c2 + d2;
        *(float*)(smem + L_SRED + (64 + l) * 4) = t4[0] + t4[1] + t4[2] + t4[3];
      }
    }
    // finalize elementwise for my (row, 4 cols)
    {
      float m3[3], rs3[3];
      #pragma unroll
      for (int g2 = 0; g2 < 3; ++g2) {
        float s1 = *(float*)(smem + L_SRED + ((2 * g2) * 16 + myrow) * 4);
        float s2 = *(float*)(smem + L_SRED + ((2 * g2 + 1) * 16 + myrow) * 4);
        float mm = s1 * (1.f / 256.f);
        float vv = s2 * (1.f / 256.f) - mm * mm;
        m3[g2] = mm; rs3[g2] = rsqrtf((vv > 0.f ? vv : 0.f) + EPS);
      }
      f32x4 g4r = *(const f32x4*)(gr + cg), b4r = *(const f32x4*)(br + cg);
      f32x4 g4z = *(const f32x4*)(gz + cg), b4z = *(const f32x4*)(bz + cg);
      f32x4 g4l = *(const f32x4*)(gl + cg), b4l = *(const f32x4*)(bl + cg);
      f32x4 cb4 = *(const f32x4*)(Chb + cg);
      bool act = t < mylen;
      f32x4 hn;
      #pragma unroll
      for (int q2 = 0; q2 < 4; ++q2) {
        float rv = 1.f / (1.f + __expf(-((pv[0][q2] - m3[0]) * rs3[0] * g4r[q2] + b4r[q2])));
        float zv = 1.f / (1.f + __expf(-((pv[1][q2] - m3[1]) * rs3[1] * g4z[q2] + b4z[q2])));
        float lv = 1.f / (1.f + __expf(-((pv[2][q2] - m3[2]) * rs3[2] * g4l[q2] + b4l[q2])));
        float n = tanhf(pv[3][q2] + rv * (pv[5][q2] + cb4[q2])) + lv * pv[4][q2];
        hn[q2] = (1.f - zv) * hreg[q2] + zv * n;
      }
      if (act) hreg = hn;
    }
    posth(par, tag);
    readhx(par, tag);

    // ======================== transition layers ========================
    #pragma unroll 1
    for (int li = 0; li < 4; ++li) {
      R = t * 5 + 1 + li; par = R & 1; tag = (unsigned)(R + 1);
      f32x4 tc0 = zero4(), tc1 = zero4(), tc2 = zero4();
      mmlds(L_TRN + (li * 3 + 0) * 8192, tc0, L_HBF);
      mmlds(L_TRN + (li * 3 + 1) * 8192, tc1, L_HBF);
      mmlds(L_TRN + (li * 3 + 2) * 8192, tc2, L_HBF);
      g6store(0, tc0); g6store(1, tc1); g6store(2, tc2);
      f32x4 qv[3];
      #pragma unroll
      for (int a2 = 0; a2 < 3; ++a2)
        qv[a2] = *(const f32x4*)(smem + L_G6 + ((a2 * 16 + myrow) * 16 + mc) * 4);
      float st4[4];
      #pragma unroll
      for (int g2 = 0; g2 < 2; ++g2) {
        f32x4 v = qv[g2];
        st4[2 * g2]     = v[0] + v[1] + v[2] + v[3];
        st4[2 * g2 + 1] = v[0] * v[0] + v[1] * v[1] + v[2] * v[2] + v[3] * v[3];
      }
      #pragma unroll
      for (int s2 = 0; s2 < 4; ++s2) {
        st4[s2] += __shfl_xor(st4[s2], 1);
        st4[s2] += __shfl_xor(st4[s2], 2);
      }
      float* sp2 = stc + par * 1536;
      ast1f(sp2 + ((l & 3) * 16 + myrow) * 16 + j, st4[l & 3]);
      waitv0();
      if (l == 0)
        __hip_atomic_store(flc + par * 16 + j, tag, __ATOMIC_RELAXED, __HIP_MEMORY_SCOPE_AGENT);
      if (li == 3) {              // prefetch next step's gate g0 units under the poll
        ldu(B0, Wsl);
        ldu(B1, Wsl + 4096);
      }
      pollf(par, tag);
      {
        float* q = sp2 + l * 16;
        f32x4 a = ald4(q), b = ald4(q + 4), c = ald4(q + 8), d = ald4(q + 12);
        f32x4 s4 = a + b + c + d;
        *(float*)(smem + L_SRED + l * 4) = s4[0] + s4[1] + s4[2] + s4[3];
      }
      bool act = t < mylen;
      {
        float m2[2], rs2[2];
        #pragma unroll
        for (int g2 = 0; g2 < 2; ++g2) {
          float s1 = *(float*)(smem + L_SRED + ((2 * g2) * 16 + myrow) * 4);
          float s2 = *(float*)(smem + L_SRED + ((2 * g2 + 1) * 16 + myrow) * 4);
          float mm = s1 * (1.f / 256.f);
          float vv = s2 * (1.f / 256.f) - mm * mm;
          m2[g2] = mm; rs2[g2] = rsqrtf((vv > 0.f ? vv : 0.f) + EPS);
        }
        f32x4 g4r = *(const f32x4*)(tgr + li * 256 + cg), b4r = *(const f32x4*)(tbr + li * 256 + cg);
        f32x4 g4z = *(const f32x4*)(tgz + li * 256 + cg), b4z = *(const f32x4*)(tbz + li * 256 + cg);
        f32x4 cb4 = *(const f32x4*)(tbc + li * 256 + cg);
        f32x4 hn;
        #pragma unroll
        for (int q2 = 0; q2 < 4; ++q2) {
          float rv = 1.f / (1.f + __expf(-((qv[0][q2] - m2[0]) * rs2[0] * g4r[q2] + b4r[q2])));
          float zv = 1.f / (1.f + __expf(-((qv[1][q2] - m2[1]) * rs2[1] * g4z[q2] + b4z[q2])));
          float n = tanhf(rv * (qv[2][q2] + cb4[q2]));
          hn[q2] = (1.f - zv) * n + zv * hreg[q2];
        }
        if (act) hreg = hn;
        if (li == 3) {
          f32x4 o = act ? hreg : zero4();
          *(f32x4*)(out + ((size_t)t * B_ + rb0 + myrow) * H_ + cg) = o;
        }
      }
      posth(par, tag);
      readhx(par, tag);
    }
  }

  // tail: zero my (row, 4 cols) past the cluster's longest sequence
  for (int t2 = maxlen; t2 < T_; ++t2)
    *(f32x4*)(out + ((size_t)t2 * B_ + rb0 + myrow) * H_ + cg) = zero4();
}

extern "C" void kernel_launch(void* const* d_in, const int* in_sizes, int n_in,
                              void* d_out, int out_size, void* d_ws, size_t ws_size,
                              hipStream_t stream) {
  const float* x    = (const float*)d_in[0];
  const int* lengths = (const int*)d_in[1];
  const float* Wr   = (const float*)d_in[2];
  const float* gr   = (const float*)d_in[3];
  const float* br   = (const float*)d_in[4];
  const float* Wz   = (const float*)d_in[5];
  const float* gz   = (const float*)d_in[6];
  const float* bz   = (const float*)d_in[7];
  const float* Wl   = (const float*)d_in[8];
  const float* gl   = (const float*)d_in[9];
  const float* bl   = (const float*)d_in[10];
  const float* Wlt  = (const float*)d_in[11];
  const float* Cx   = (const float*)d_in[12];
  const float* Chw  = (const float*)d_in[13];
  const float* Chb  = (const float*)d_in[14];
  const float* tWr  = (const float*)d_in[15];
  const float* tgr  = (const float*)d_in[16];
  const float* tbr  = (const float*)d_in[17];
  const float* tWz  = (const float*)d_in[18];
  const float* tgz  = (const float*)d_in[19];
  const float* tbz  = (const float*)d_in[20];
  const float* tWc  = (const float*)d_in[21];
  const float* tbc  = (const float*)d_in[22];

  short*    wt    = (short*)d_ws;
  float*    stats = (float*)((char*)d_ws + STATS_OFFB);
  ull*      hx8   = (ull*)((char*)d_ws + HX_OFFB);
  unsigned* flags = (unsigned*)((char*)d_ws + FLAG_OFFB);

  // reset tagged h arena + flags (kills stale tags across graph replays)
  hipMemsetAsync((char*)d_ws + SYNC0_OFFB, 0, SYNC0_BYTES, stream);
  hipLaunchKernelGGL(prep_weights, dim3((WT_TOTAL + 255) / 256), dim3(256), 0, stream,
                     Wr, Wz, Wl, Wlt, Cx, Chw, tWr, tWz, tWc, wt);
  hipLaunchKernelGGL(rnn_sx, dim3(128), dim3(64), 0, stream,
                     x, lengths, gr, br, gz, bz, gl, bl, Chb,
                     tgr, tbr, tgz, tbz, tbc, wt, stats, hx8, flags, (float*)d_out);
}